// Round 11
// baseline (94.080 us; speedup 1.0000x reference)
//
#include <hip/hip_runtime.h>
#include <stdint.h>

#define S_LEN 4096
#define HQ 32
#define HKV 8
#define DD 128
#define QBLK 128
#define KVROW (HKV * DD)

typedef __attribute__((ext_vector_type(8)))  __bf16 bf16x8;
typedef __attribute__((ext_vector_type(2)))  __bf16 bf16x2;
typedef __attribute__((ext_vector_type(4)))  float  f32x4;
typedef __attribute__((ext_vector_type(2)))  unsigned int u32x2;
typedef __attribute__((ext_vector_type(4)))  unsigned int u32x4;

// RNE f32x2 -> packed bf16x2 (compiler emits v_cvt_pk_bf16_f32).
__device__ __forceinline__ unsigned int pk2(float lo, float hi2) {
  bf16x2 t = {(__bf16)lo, (__bf16)hi2};
  return __builtin_bit_cast(unsigned int, t);
}
__device__ __forceinline__ bf16x8 mk8(unsigned int w0, unsigned int w1,
                                      unsigned int w2, unsigned int w3) {
  u32x4 u = {w0, w1, w2, w3};
  return __builtin_bit_cast(bf16x8, u);
}

// V swizzle: full-rank in d. Read side (d = dt*16+l15): slot = (l15^dt) ->
// 16 lanes hit 16 distinct 8B slots (was 4-way conflicted with (d&28)<<2).
// Write side (d = 4*dc+j): slot mixes dc&3 AND dc>>2 -> 2-way (free).
#define SWZV(d) ((((d) & 15) ^ ((d) >> 4)) << 3)

// 16 waves x 2 sequential 16q-units each. Unit live set ~80 regs -> fits the
// 128-reg unified budget (VGPR+AGPR) needed for 4 waves/SIMD.
__global__ __launch_bounds__(1024, 1)
void swa_fwd(const float* __restrict__ Qg, const float* __restrict__ Kg,
             const float* __restrict__ Vg, float* __restrict__ Og) {
  // K window: bf16 [c:256][d:128], row 256B, swizzle byte^=(c&15)<<4
  // V window: bf16 transposed [d:128][c:256], row 512B, swizzle SWZV(d)
  __shared__ __align__(16) unsigned char Kl[65536];
  __shared__ __align__(16) unsigned char Vl[65536];

  // XCD-aware bijective swizzle (nwg = 512, divisible by 8).
  const int nwg  = gridDim.x;
  const int bid0 = blockIdx.x;
  const int bid  = (bid0 & 7) * (nwg >> 3) + (bid0 >> 3);

  const int n    = bid & 31;          // q-block index
  const int hkv  = (bid >> 5) & 7;
  const int b    = bid >> 8;
  const int tid  = threadIdx.x;
  const int lane = tid & 63;
  const int wv   = tid >> 6;          // 0..15
  const int g    = lane >> 4;         // 16-lane group 0..3
  const int l15  = lane & 15;

  // ---------------- stage K/V window (keys (n-1)*128 .. n*128+127) ----------------
  #pragma unroll
  for (int i = 0; i < 8; ++i) {
    const int e  = i * 1024 + tid;    // 8192 float4-chunks = 256 rows x 32 chunks
    const int c  = e >> 5;            // window key index 0..255
    const int dc = e & 31;            // float4 index within d
    const int tk = (n - 1) * QBLK + c;
    f32x4 xk = {0.f, 0.f, 0.f, 0.f};
    f32x4 xv = {0.f, 0.f, 0.f, 0.f};
    if (tk >= 0) {
      const size_t base = (size_t)(b * S_LEN + tk) * KVROW + hkv * DD + dc * 4;
      xk = *(const f32x4*)(Kg + base);
      xv = *(const f32x4*)(Vg + base);
    }
    u32x2 kw = { pk2(xk[0], xk[1]), pk2(xk[2], xk[3]) };
    *(u32x2*)(&Kl[c * 256 + ((dc * 8) ^ ((c & 15) << 4))]) = kw;
    #pragma unroll
    for (int j = 0; j < 4; ++j) {     // transposed scatter for V
      const int d = dc * 4 + j;
      *(unsigned short*)(&Vl[d * 512 + ((c * 2) ^ SWZV(d))]) =
          __builtin_bit_cast(unsigned short, (__bf16)xv[j]);
    }
  }
  __syncthreads();

  const float SC = 0.08838834764831845f * 1.44269504088896340f; // 1/sqrt(128)*log2e

  // 32 units = 4 heads x 8 16-row q-chunks; wave wv owns units wv*2, wv*2+1.
  #pragma unroll 1
  for (int uu = 0; uu < 2; ++uu) {
    const int uid   = wv * 2 + uu;
    const int h     = hkv * 4 + (uid >> 3);
    const int chunk = uid & 7;
    const int qs    = chunk * 16;

    // Q fragments (B-operand of swapped QK^T): col q = l15, k-octet = g.
    const float* qp = Qg + (size_t)(b * S_LEN + n * QBLK + qs + l15) * (HQ * DD)
                      + h * DD + g * 8;
    bf16x8 qf[4];
    #pragma unroll
    for (int dc = 0; dc < 4; ++dc) {
      f32x4 a  = *(const f32x4*)(qp + dc * 32);
      f32x4 c4 = *(const f32x4*)(qp + dc * 32 + 4);
      qf[dc] = mk8(pk2(a[0], a[1]), pk2(a[2], a[3]),
                   pk2(c4[0], c4[1]), pk2(c4[2], c4[3]));
    }

    // O^T accumulators: o[dt] covers d = dt*16 + g*4 + r, q = l15.
    f32x4 o[8];
    #pragma unroll
    for (int dt = 0; dt < 8; ++dt) o[dt] = (f32x4){0.f, 0.f, 0.f, 0.f};
    float ls = 0.f;

    // 9 16-key tiles (window tiles chunk..chunk+8), processed in pairs.
    #pragma unroll
    for (int pp = 0; pp < 5; ++pp) {
      const int tt0 = 2 * pp, tt1 = 2 * pp + 1;
      // n==0: tiles with (chunk+tt)*16 < 128 are fully masked (left pad).
      if (n == 0 && chunk + tt1 < 8) continue;   // both tiles dead

      unsigned int w0 = 0, w1 = 0, w2 = 0, w3 = 0;

      // ---- tile tt0: S^T = K_tile * Q^T (4 MFMAs over d) ----
      if (!(n == 0 && chunk + tt0 < 8)) {
        const int c = (chunk + tt0) * 16 + l15;   // key row (A: row=l15)
        f32x4 acc = {0.f, 0.f, 0.f, 0.f};
        __builtin_amdgcn_s_setprio(1);
        #pragma unroll
        for (int dc = 0; dc < 4; ++dc) {
          const bf16x8 kf = *(const bf16x8*)(
              &Kl[c * 256 + ((dc * 64 + g * 16) ^ ((c & 15) << 4))]);
          acc = __builtin_amdgcn_mfma_f32_16x16x32_bf16(kf, qf[dc], acc, 0, 0, 0);
        }
        __builtin_amdgcn_s_setprio(0);
        // mask: tt0==0: g4r>l15 ; tt0==8: g4r<=l15 ; else all valid.
        float p[4];
        #pragma unroll
        for (int r = 0; r < 4; ++r) {
          const int g4r = g * 4 + r;
          const float e = __builtin_amdgcn_exp2f(acc[r] * SC);
          bool valid = true;
          if (pp == 0) valid = (g4r > l15);
          if (pp == 4) valid = (g4r <= l15);
          p[r] = valid ? e : 0.f;
          ls += p[r];
        }
        w0 = pk2(p[0], p[1]);
        w1 = pk2(p[2], p[3]);
      }

      // ---- tile tt1 (pp<4 only; tt1 in {1,3,5,7} -> never needs a mask) ----
      if (pp < 4 && !(n == 0 && chunk + tt1 < 8)) {
        const int c = (chunk + tt1) * 16 + l15;
        f32x4 acc = {0.f, 0.f, 0.f, 0.f};
        __builtin_amdgcn_s_setprio(1);
        #pragma unroll
        for (int dc = 0; dc < 4; ++dc) {
          const bf16x8 kf = *(const bf16x8*)(
              &Kl[c * 256 + ((dc * 64 + g * 16) ^ ((c & 15) << 4))]);
          acc = __builtin_amdgcn_mfma_f32_16x16x32_bf16(kf, qf[dc], acc, 0, 0, 0);
        }
        __builtin_amdgcn_s_setprio(0);
        float p0 = __builtin_amdgcn_exp2f(acc[0] * SC);
        float p1 = __builtin_amdgcn_exp2f(acc[1] * SC);
        float p2 = __builtin_amdgcn_exp2f(acc[2] * SC);
        float p3 = __builtin_amdgcn_exp2f(acc[3] * SC);
        ls += p0 + p1 + p2 + p3;
        w2 = pk2(p0, p1);
        w3 = pk2(p2, p3);
      }

      // ---- PV with co-permuted key order: B = P^T in-register already;
      //      A (V^T) reads keys {tt0: g*4..+3, tt1: g*4..+3} to match. ----
      const bf16x8 pf = mk8(w0, w1, w2, w3);
      const int ck0 = ((chunk + tt0) * 16 + g * 4) * 2;              // byte col
      const int ck1 = (pp < 4) ? ((chunk + tt1) * 16 + g * 4) * 2 : ck0;
      __builtin_amdgcn_s_setprio(1);
      #pragma unroll
      for (int dt = 0; dt < 8; ++dt) {
        const int d  = dt * 16 + l15;       // A row = l15 within d-tile
        const int rb = d * 512;
        const int sz = SWZV(d);
        const u32x2 a0 = *(const u32x2*)(&Vl[rb + (ck0 ^ sz)]);
        const u32x2 a1 = *(const u32x2*)(&Vl[rb + (ck1 ^ sz)]);
        const bf16x8 vf = mk8(a0[0], a0[1], a1[0], a1[1]);
        o[dt] = __builtin_amdgcn_mfma_f32_16x16x32_bf16(vf, pf, o[dt], 0, 0, 0);
      }
      __builtin_amdgcn_s_setprio(0);
    }

    // ---- softmax denominator: all outputs of this lane share q = l15 ----
    ls += __shfl_xor(ls, 16);
    ls += __shfl_xor(ls, 32);
    const float inv = 1.0f / ls;

    float* op = Og + (size_t)(b * S_LEN + n * QBLK + qs + l15) * (HQ * DD)
                + h * DD + g * 4;
    #pragma unroll
    for (int dt = 0; dt < 8; ++dt) {
      f32x4 v = o[dt];
      v[0] *= inv; v[1] *= inv; v[2] *= inv; v[3] *= inv;
      *(f32x4*)(op + dt * 16) = v;
    }
  }
}

extern "C" void kernel_launch(void* const* d_in, const int* in_sizes, int n_in,
                              void* d_out, int out_size, void* d_ws, size_t ws_size,
                              hipStream_t stream) {
  const float* Q = (const float*)d_in[0];
  const float* K = (const float*)d_in[1];
  const float* V = (const float*)d_in[2];
  float* O = (float*)d_out;
  const int B = in_sizes[0] / (S_LEN * HQ * DD);
  const int nblocks = B * HKV * (S_LEN / QBLK);   // b-major, then hkv, then n
  swa_fwd<<<dim3(nblocks), dim3(1024), 0, stream>>>(Q, K, V, O);
}

// Round 12
// 85.685 us; speedup vs baseline: 1.0980x; 1.0980x over previous
//
#include <hip/hip_runtime.h>
#include <stdint.h>

#define S_LEN 4096
#define HQ 32
#define HKV 8
#define DD 128
#define QBLK 128
#define KVROW (HKV * DD)

typedef __attribute__((ext_vector_type(8)))  __bf16 bf16x8;
typedef __attribute__((ext_vector_type(2)))  __bf16 bf16x2;
typedef __attribute__((ext_vector_type(4)))  float  f32x4;
typedef __attribute__((ext_vector_type(2)))  unsigned int u32x2;
typedef __attribute__((ext_vector_type(4)))  unsigned int u32x4;

// RNE f32x2 -> packed bf16x2 (compiler emits v_cvt_pk_bf16_f32).
__device__ __forceinline__ unsigned int pk2(float lo, float hi2) {
  bf16x2 t = {(__bf16)lo, (__bf16)hi2};
  return __builtin_bit_cast(unsigned int, t);
}
__device__ __forceinline__ bf16x8 mk8(unsigned int w0, unsigned int w1,
                                      unsigned int w2, unsigned int w3) {
  u32x4 u = {w0, w1, w2, w3};
  return __builtin_bit_cast(bf16x8, u);
}

// V swizzle, 64-byte XOR window (V rows are 320 B, so a 128-B window would
// escape the row at cols >= 256). Read: lanes l15 and l15+8 share a slot but
// their rows differ by 8*320B = 0 mod 128B -> 2-way (free, m136).
#define SWZV(d) ((((d) & 7) ^ (((d) >> 4) & 7)) << 3)

// Sliding-window split: each 512-thread block owns 32 q-rows (2 chunks x
// 4 heads = 8 units = 8 waves) and stages only its 160-key window:
// K 160x256B + V^T 128x320B = 80 KiB -> 2 blocks/CU, phase-decorrelated
// (block B computes while block A stages). launch_bounds(512,4) pins the
// 128-unified-reg budget; single-unit live set ~84 fits.
__global__ __launch_bounds__(512, 4)
void swa_fwd(const float* __restrict__ Qg, const float* __restrict__ Kg,
             const float* __restrict__ Vg, float* __restrict__ Og) {
  __shared__ __align__(16) unsigned char Kl[40960];  // [c:160][d:128] bf16
  __shared__ __align__(16) unsigned char Vl[40960];  // V^T [d:128][c:160] bf16

  // XCD-aware bijective swizzle (nwg = 2048, divisible by 8): consecutive
  // logical blocks (adjacent j, overlapping 128 keys) share an XCD L2.
  const int nwg  = gridDim.x;
  const int bid0 = blockIdx.x;
  const int bid  = (bid0 & 7) * (nwg >> 3) + (bid0 >> 3);

  const int j    = bid & 3;           // 32-row sub-block within the q-block
  const int n    = (bid >> 2) & 31;   // q-block index
  const int hkv  = (bid >> 7) & 7;
  const int b    = bid >> 10;
  const int tid  = threadIdx.x;
  const int lane = tid & 63;
  const int wv   = tid >> 6;          // 0..7
  const int g    = lane >> 4;         // 16-lane group 0..3
  const int l15  = lane & 15;

  // ---- stage the 160-key window: global keys kbase .. kbase+159 ----
  const int kbase = (n - 1) * QBLK + 32 * j;
  #pragma unroll
  for (int i = 0; i < 10; ++i) {
    const int e  = i * 512 + tid;     // 5120 float4-chunks = 160 rows x 32
    const int c  = e >> 5;            // window key index 0..159
    const int dc = e & 31;            // float4 index within d
    const int tk = kbase + c;
    f32x4 xk = {0.f, 0.f, 0.f, 0.f};
    f32x4 xv = {0.f, 0.f, 0.f, 0.f};
    if (tk >= 0) {                    // n==0 left padding only
      const size_t base = (size_t)(b * S_LEN + tk) * KVROW + hkv * DD + dc * 4;
      xk = *(const f32x4*)(Kg + base);
      xv = *(const f32x4*)(Vg + base);
    }
    u32x2 kw = { pk2(xk[0], xk[1]), pk2(xk[2], xk[3]) };
    *(u32x2*)(&Kl[c * 256 + ((dc * 8) ^ ((c & 15) << 4))]) = kw;
    #pragma unroll
    for (int j4 = 0; j4 < 4; ++j4) {  // transposed scatter for V
      const int d = dc * 4 + j4;
      *(unsigned short*)(&Vl[d * 320 + ((c * 2) ^ SWZV(d))]) =
          __builtin_bit_cast(unsigned short, (__bf16)xv[j4]);
    }
  }
  __syncthreads();

  const float SC = 0.08838834764831845f * 1.44269504088896340f; // 1/sqrt(128)*log2e

  // 8 units = 4 heads x 2 local 16-row q-chunks; one unit per wave.
  const int cc = wv & 1;              // local chunk 0..1
  const int h  = hkv * 4 + (wv >> 1);
  const int cg = 2 * j + cc;          // global chunk 0..7 (n==0 masking)
  const int qrow = n * QBLK + 32 * j + cc * 16 + l15;

  // Q fragments (B-operand of swapped QK^T): col q = l15, k-octet = g.
  const float* qp = Qg + (size_t)(b * S_LEN + qrow) * (HQ * DD) + h * DD + g * 8;
  bf16x8 qf[4];
  #pragma unroll
  for (int dc = 0; dc < 4; ++dc) {
    f32x4 a  = *(const f32x4*)(qp + dc * 32);
    f32x4 c4 = *(const f32x4*)(qp + dc * 32 + 4);
    qf[dc] = mk8(pk2(a[0], a[1]), pk2(a[2], a[3]),
                 pk2(c4[0], c4[1]), pk2(c4[2], c4[3]));
  }

  // O^T accumulators: o[dt] covers d = dt*16 + g*4 + r, q = l15.
  f32x4 o[8];
  #pragma unroll
  for (int dt = 0; dt < 8; ++dt) o[dt] = (f32x4){0.f, 0.f, 0.f, 0.f};
  float ls = 0.f;

  // 9 16-key tiles (local tiles cc..cc+8 in the 10-tile buffer), in pairs.
  #pragma unroll
  for (int pp = 0; pp < 5; ++pp) {
    const int tt0 = 2 * pp, tt1 = 2 * pp + 1;
    // n==0: window tiles with cg+tt < 8 are fully masked (left pad).
    if (n == 0 && cg + tt1 < 8) continue;   // both tiles dead

    unsigned int w0 = 0, w1 = 0, w2 = 0, w3 = 0;

    // ---- tile tt0: S^T = K_tile * Q^T (4 MFMAs over d) ----
    if (!(n == 0 && cg + tt0 < 8)) {
      const int c = (cc + tt0) * 16 + l15;   // key row (A: row=l15)
      f32x4 acc = {0.f, 0.f, 0.f, 0.f};
      __builtin_amdgcn_s_setprio(1);
      #pragma unroll
      for (int dc = 0; dc < 4; ++dc) {
        const bf16x8 kf = *(const bf16x8*)(
            &Kl[c * 256 + ((dc * 64 + g * 16) ^ ((c & 15) << 4))]);
        acc = __builtin_amdgcn_mfma_f32_16x16x32_bf16(kf, qf[dc], acc, 0, 0, 0);
      }
      __builtin_amdgcn_s_setprio(0);
      // mask: tt0==0: g4r>l15 ; tt0==8: g4r<=l15 ; else all valid.
      float p[4];
      #pragma unroll
      for (int r = 0; r < 4; ++r) {
        const int g4r = g * 4 + r;
        const float e = __builtin_amdgcn_exp2f(acc[r] * SC);
        bool valid = true;
        if (pp == 0) valid = (g4r > l15);
        if (pp == 4) valid = (g4r <= l15);
        p[r] = valid ? e : 0.f;
        ls += p[r];
      }
      w0 = pk2(p[0], p[1]);
      w1 = pk2(p[2], p[3]);
    }

    // ---- tile tt1 (pp<4 only; interior tiles never need a mask) ----
    if (pp < 4 && !(n == 0 && cg + tt1 < 8)) {
      const int c = (cc + tt1) * 16 + l15;
      f32x4 acc = {0.f, 0.f, 0.f, 0.f};
      __builtin_amdgcn_s_setprio(1);
      #pragma unroll
      for (int dc = 0; dc < 4; ++dc) {
        const bf16x8 kf = *(const bf16x8*)(
            &Kl[c * 256 + ((dc * 64 + g * 16) ^ ((c & 15) << 4))]);
        acc = __builtin_amdgcn_mfma_f32_16x16x32_bf16(kf, qf[dc], acc, 0, 0, 0);
      }
      __builtin_amdgcn_s_setprio(0);
      float p0 = __builtin_amdgcn_exp2f(acc[0] * SC);
      float p1 = __builtin_amdgcn_exp2f(acc[1] * SC);
      float p2 = __builtin_amdgcn_exp2f(acc[2] * SC);
      float p3 = __builtin_amdgcn_exp2f(acc[3] * SC);
      ls += p0 + p1 + p2 + p3;
      w2 = pk2(p0, p1);
      w3 = pk2(p2, p3);
    }

    // ---- PV with co-permuted key order: B = P^T in-register already;
    //      A (V^T) reads keys {tt0: g*4..+3, tt1: g*4..+3} to match. ----
    const bf16x8 pf = mk8(w0, w1, w2, w3);
    const int ck0 = ((cc + tt0) * 16 + g * 4) * 2;              // byte col
    const int ck1 = (pp < 4) ? ((cc + tt1) * 16 + g * 4) * 2 : ck0;
    __builtin_amdgcn_s_setprio(1);
    #pragma unroll
    for (int dt = 0; dt < 8; ++dt) {
      const int d  = dt * 16 + l15;       // A row = l15 within d-tile
      const int rb = d * 320;
      const int sz = SWZV(d);
      const u32x2 a0 = *(const u32x2*)(&Vl[rb + (ck0 ^ sz)]);
      const u32x2 a1 = *(const u32x2*)(&Vl[rb + (ck1 ^ sz)]);
      const bf16x8 vf = mk8(a0[0], a0[1], a1[0], a1[1]);
      o[dt] = __builtin_amdgcn_mfma_f32_16x16x32_bf16(vf, pf, o[dt], 0, 0, 0);
    }
    __builtin_amdgcn_s_setprio(0);
  }

  // ---- softmax denominator: all outputs of this lane share q = l15 ----
  ls += __shfl_xor(ls, 16);
  ls += __shfl_xor(ls, 32);
  const float inv = 1.0f / ls;

  float* op = Og + (size_t)(b * S_LEN + qrow) * (HQ * DD) + h * DD + g * 4;
  #pragma unroll
  for (int dt = 0; dt < 8; ++dt) {
    f32x4 v = o[dt];
    v[0] *= inv; v[1] *= inv; v[2] *= inv; v[3] *= inv;
    *(f32x4*)(op + dt * 16) = v;
  }
}

extern "C" void kernel_launch(void* const* d_in, const int* in_sizes, int n_in,
                              void* d_out, int out_size, void* d_ws, size_t ws_size,
                              hipStream_t stream) {
  const float* Q = (const float*)d_in[0];
  const float* K = (const float*)d_in[1];
  const float* V = (const float*)d_in[2];
  float* O = (float*)d_out;
  const int B = in_sizes[0] / (S_LEN * HQ * DD);
  const int nblocks = B * HKV * (S_LEN / QBLK) * 4;   // b, hkv, n, j (j fastest)
  swa_fwd<<<dim3(nblocks), dim3(512), 0, stream>>>(Q, K, V, O);
}